// Round 1
// baseline (499.646 us; speedup 1.0000x reference)
//
#include <hip/hip_runtime.h>

#define NN 512
#define MM 512
#define KD 64
#define BIGF 1e30f
#define LOG2E 1.4426950408889634f
#define LN2F 0.6931471805599453f

// ---------------------------------------------------------------------------
// Kernel A: D[b,i,j] = ||x_i||^2 + ||y_j||^2 - 2 x_i . y_j
// grid (MM/64, NN/64, B), block 256 (16x16), each thread does a 4x4 register
// tile over K=64 staged in LDS. Stride-65 LDS rows -> conflict-free/2-way.
// ---------------------------------------------------------------------------
__global__ __launch_bounds__(256) void compute_D_kernel(
    const float* __restrict__ x, const float* __restrict__ y,
    float* __restrict__ D) {
  __shared__ float xs[64][65];
  __shared__ float ys[64][65];
  __shared__ float x2s[64];
  __shared__ float y2s[64];

  const int b   = blockIdx.z;
  const int i0  = blockIdx.y * 64;
  const int j0  = blockIdx.x * 64;
  const int tid = threadIdx.x;

  const float4* xg = (const float4*)(x + ((size_t)b * NN + i0) * KD);
  const float4* yg = (const float4*)(y + ((size_t)b * MM + j0) * KD);
#pragma unroll
  for (int u = 0; u < 4; ++u) {
    int idx = tid + u * 256;   // 0..1023
    int row = idx >> 4;        // 64 rows
    int c4  = idx & 15;        // 16 float4 per row (K=64)
    float4 v = xg[row * 16 + c4];
    xs[row][c4 * 4 + 0] = v.x; xs[row][c4 * 4 + 1] = v.y;
    xs[row][c4 * 4 + 2] = v.z; xs[row][c4 * 4 + 3] = v.w;
    float4 w = yg[row * 16 + c4];
    ys[row][c4 * 4 + 0] = w.x; ys[row][c4 * 4 + 1] = w.y;
    ys[row][c4 * 4 + 2] = w.z; ys[row][c4 * 4 + 3] = w.w;
  }
  __syncthreads();

  // Row/col squared norms (threads 0..127 only; no barrier divergence).
  if (tid < 64) {
    float s = 0.f;
#pragma unroll
    for (int k = 0; k < KD; ++k) { float a = xs[tid][k]; s = fmaf(a, a, s); }
    x2s[tid] = s;
  } else if (tid < 128) {
    int r = tid - 64;
    float s = 0.f;
#pragma unroll
    for (int k = 0; k < KD; ++k) { float a = ys[r][k]; s = fmaf(a, a, s); }
    y2s[r] = s;
  }

  const int tx = tid & 15;
  const int ty = tid >> 4;
  float acc[4][4];
#pragma unroll
  for (int r = 0; r < 4; ++r)
#pragma unroll
    for (int c = 0; c < 4; ++c) acc[r][c] = 0.f;

#pragma unroll 4
  for (int k = 0; k < KD; ++k) {
    float a0 = xs[ty * 4 + 0][k];
    float a1 = xs[ty * 4 + 1][k];
    float a2 = xs[ty * 4 + 2][k];
    float a3 = xs[ty * 4 + 3][k];
    float b0 = ys[tx * 4 + 0][k];
    float b1 = ys[tx * 4 + 1][k];
    float b2 = ys[tx * 4 + 2][k];
    float b3 = ys[tx * 4 + 3][k];
    acc[0][0] = fmaf(a0, b0, acc[0][0]); acc[0][1] = fmaf(a0, b1, acc[0][1]);
    acc[0][2] = fmaf(a0, b2, acc[0][2]); acc[0][3] = fmaf(a0, b3, acc[0][3]);
    acc[1][0] = fmaf(a1, b0, acc[1][0]); acc[1][1] = fmaf(a1, b1, acc[1][1]);
    acc[1][2] = fmaf(a1, b2, acc[1][2]); acc[1][3] = fmaf(a1, b3, acc[1][3]);
    acc[2][0] = fmaf(a2, b0, acc[2][0]); acc[2][1] = fmaf(a2, b1, acc[2][1]);
    acc[2][2] = fmaf(a2, b2, acc[2][2]); acc[2][3] = fmaf(a2, b3, acc[2][3]);
    acc[3][0] = fmaf(a3, b0, acc[3][0]); acc[3][1] = fmaf(a3, b1, acc[3][1]);
    acc[3][2] = fmaf(a3, b2, acc[3][2]); acc[3][3] = fmaf(a3, b3, acc[3][3]);
  }
  __syncthreads();   // x2s/y2s ready

  float yq[4];
#pragma unroll
  for (int c = 0; c < 4; ++c) yq[c] = y2s[tx * 4 + c];
#pragma unroll
  for (int r = 0; r < 4; ++r) {
    float xq = x2s[ty * 4 + r];
    float4 o;
    o.x = xq + yq[0] - 2.f * acc[r][0];
    o.y = xq + yq[1] - 2.f * acc[r][1];
    o.z = xq + yq[2] - 2.f * acc[r][2];
    o.w = xq + yq[3] - 2.f * acc[r][3];
    float4* dst =
        (float4*)(D + ((size_t)b * NN + i0 + ty * 4 + r) * MM + j0 + tx * 4);
    *dst = o;
  }
}

// ---------------------------------------------------------------------------
// Kernel B: softDTW anti-diagonal DP. One block per batch, thread i owns row i.
// Triple-buffered LDS ring -> one __syncthreads per diagonal. r2 (left
// neighbor, same row) lives in a register. log2-domain softmin:
//   softmin' = mn - log2( 2^(mn-r0) + 2^(mn-r1) + 2^(mn-r2) ),  R' = R*log2e
// ---------------------------------------------------------------------------
__global__ __launch_bounds__(512) void softdtw_dp_kernel(
    const float* __restrict__ D, float* __restrict__ out) {
  __shared__ float buf[3][NN];
  const int b = blockIdx.x;
  const int i = threadIdx.x;
  const float* __restrict__ Drow = D + ((size_t)b * NN + i) * MM;

  float my_prev = BIGF;                 // R'(i, j-1), BIG when j-1 invalid
  const int im = (i == 0) ? 0 : i - 1;  // clamped neighbor index
  const bool has_up = (i >= 1);

  // rotating buffer indices: write pw, read pm1 (p-1), pm2 (p-2)
  int pw = 0, pm1 = 2, pm2 = 1;

  float Dld = Drow[0];  // prefetch for p=0 (j=0-i clamped; masked unless i==0)

  for (int p = 0; p < NN + MM - 1; ++p) {
    const int j = p - i;
    const bool valid = (j >= 0) & (j < MM);
    const float Dcur = Dld;
    int jn = j + 1;
    jn = jn < 0 ? 0 : (jn > MM - 1 ? MM - 1 : jn);
    Dld = Drow[jn];  // prefetch next diagonal (hidden behind compute+barrier)

    float r1v = buf[pm1][im];
    float r0v = buf[pm2][im];
    float r1 = has_up ? r1v : BIGF;
    float r0 = (has_up && j >= 1) ? r0v : ((i == 0 && j == 0) ? 0.f : BIGF);
    float r2 = my_prev;

    float mn = fminf(r0, fminf(r1, r2));
    float e0 = __builtin_amdgcn_exp2f(mn - r0);
    float e1 = __builtin_amdgcn_exp2f(mn - r1);
    float e2 = __builtin_amdgcn_exp2f(mn - r2);
    float sm = mn - __builtin_amdgcn_logf(e0 + e1 + e2);  // v_log_f32 = log2
    float newv = valid ? fmaf(Dcur, LOG2E, sm) : BIGF;

    buf[pw][i] = newv;
    my_prev = newv;

    int t = pm2; pm2 = pm1; pm1 = pw; pw = t;
    __syncthreads();
  }

  if (i == NN - 1) out[b] = my_prev * LN2F;
}

// ---------------------------------------------------------------------------
extern "C" void kernel_launch(void* const* d_in, const int* in_sizes, int n_in,
                              void* d_out, int out_size, void* d_ws,
                              size_t ws_size, hipStream_t stream) {
  const float* x = (const float*)d_in[0];
  const float* y = (const float*)d_in[1];
  float* out = (float*)d_out;
  float* D = (float*)d_ws;  // needs B*512*512*4 = 64 MB

  const int B = in_sizes[0] / (NN * KD);

  dim3 gA(MM / 64, NN / 64, B);
  compute_D_kernel<<<gA, 256, 0, stream>>>(x, y, D);
  softdtw_dp_kernel<<<B, NN, 0, stream>>>(D, out);
}